// Round 5
// baseline (129.611 us; speedup 1.0000x reference)
//
#include <hip/hip_runtime.h>

// AnchorTarget (pysot) for b=128, G=64, SCORE=25, A=5, STRIDE=8.
// Outputs concatenated as float32: cls(128,5,25,25) | bt(128,4,5,25,25) |
// bw(128,5,25,25) | max_ov(128,3125). Total 2,800,000 floats.
//
// Round 5: 3 dispatches, no cooperative launch (r4's coop kernel never ran).
//   K1: gtmax[b,g] wave-per-(b,g) (r3-validated) + zero poscnt
//   K2: per-anchor row (5 blk/batch x 625 n): cls0/max_ov coalesced,
//       bt via LDS transpose -> contiguous 125-float runs,
//       batch-127 positive count -> poscnt (device atomicAdd)
//   K3: caps scan + cls AND bw written coalesced via LDS transpose
// keep-test float equality protected by contract(off) in shared iou_f.

namespace {
constexpr int B_   = 128;
constexpr int N_   = 3125;   // 25*25*5
constexpr int G_   = 64;
constexpr int A_   = 5;
constexpr int S_   = 25;
constexpr int POSN = 16;
constexpr int TOTN = 64;

constexpr int CLS_OFF = 0;
constexpr int BT_OFF  = B_ * A_ * S_ * S_;              // 400000
constexpr int BW_OFF  = BT_OFF + B_ * 4 * A_ * S_ * S_; // 2000000
constexpr int MO_OFF  = BW_OFF + B_ * A_ * S_ * S_;     // 2400000
}

__device__ __forceinline__ float area_f(float x0, float y0, float x1, float y1) {
#pragma clang fp contract(off)
  return ((x1 - x0) + 1.0f) * ((y1 - y0) + 1.0f);
}

__device__ __forceinline__ float iou_f(float a0, float a1, float a2, float a3,
                                       float aarea, float g0, float g1,
                                       float g2, float g3, float garea) {
#pragma clang fp contract(off)
  // exactly mirrors numpy op order: ((min-max)+1), clip, mul, (a+g)-inter, div
  float ix = (fminf(a2, g2) - fmaxf(a0, g0)) + 1.0f;
  float iy = (fminf(a3, g3) - fmaxf(a1, g1)) + 1.0f;
  ix = fmaxf(ix, 0.0f);
  iy = fmaxf(iy, 0.0f);
  float inter = ix * iy;
  return inter / ((aarea + garea) - inter);
}

// ---- K1: gt_max[b][g] = max_n iou(n,g); also zero poscnt ------------------
__global__ __launch_bounds__(256) void k1_gtmax(
    const float* __restrict__ gt,       // (128,64,4)
    const float* __restrict__ anchors,  // (3125,4)
    float* __restrict__ gtmax,          // (128,64)
    int* __restrict__ poscnt) {
#pragma clang fp contract(off)
  if (blockIdx.x == 0 && threadIdx.x == 0) poscnt[0] = 0;

  const int t    = threadIdx.x;
  const int lane = t & 63;
  const int W    = blockIdx.x * 4 + (t >> 6);  // 0..8191
  const int b    = W >> 6;
  const int g    = W & 63;

  const float4 gg = ((const float4*)gt)[b * G_ + g];  // wave-uniform
  const float garea = area_f(gg.x, gg.y, gg.z, gg.w);

  float gmax = 0.0f;  // iou >= 0
#pragma unroll 4
  for (int i = 0; i < 48; ++i) {
    const int n = i * 64 + lane;
    const float4 aa = ((const float4*)anchors)[n];
    const float aarea = area_f(aa.x, aa.y, aa.z, aa.w);
    gmax = fmaxf(gmax, iou_f(aa.x, aa.y, aa.z, aa.w, aarea,
                             gg.x, gg.y, gg.z, gg.w, garea));
  }
  {
    const int n = 48 * 64 + lane;
    if (n < N_) {
      const float4 aa = ((const float4*)anchors)[n];
      const float aarea = area_f(aa.x, aa.y, aa.z, aa.w);
      gmax = fmaxf(gmax, iou_f(aa.x, aa.y, aa.z, aa.w, aarea,
                               gg.x, gg.y, gg.z, gg.w, garea));
    }
  }
#pragma unroll
  for (int off = 32; off > 0; off >>= 1)
    gmax = fmaxf(gmax, __shfl_xor(gmax, off, 64));

  if (lane == 0) gtmax[b * G_ + g] = gmax;
}

// ---- K2: per-anchor row -> cls0, bt (LDS-transposed), max_ov, poscnt ------
// Grid (5, 128): block q covers n in [625q, 625q+625) of batch b.
__global__ __launch_bounds__(256) void k2_anchor(
    const float* __restrict__ gt, const float* __restrict__ anchors,
    const float* __restrict__ gtmax, float* __restrict__ out,
    int* __restrict__ cls0, int* __restrict__ poscnt) {
#pragma clang fp contract(off)
  const int b = blockIdx.y;
  const int q = blockIdx.x;
  const int t = threadIdx.x;

  __shared__ float s_gt[G_ * 4];
  __shared__ float s_garea[G_];
  __shared__ float s_gtmax[G_];
  __shared__ float s_bt[4][625];
  __shared__ int   s_pc;

  if (t == 0) s_pc = 0;
  if (t < G_) {
    const float4 gg = ((const float4*)gt)[b * G_ + t];
    s_gt[t * 4 + 0] = gg.x;
    s_gt[t * 4 + 1] = gg.y;
    s_gt[t * 4 + 2] = gg.z;
    s_gt[t * 4 + 3] = gg.w;
    s_garea[t] = area_f(gg.x, gg.y, gg.z, gg.w);
    const float v = gtmax[b * G_ + t];
    s_gtmax[t] = (v == 0.0f) ? 1e-5f : v;
  }
  __syncthreads();

#pragma unroll
  for (int pass = 0; pass < 3; ++pass) {
    const int nl = pass * 256 + t;  // local n in [0,625)
    if (nl >= 625) break;
    const int n = q * 625 + nl;     // global anchor id, < 3125

    const float4 aa = ((const float4*)anchors)[n];
    const float aw = (aa.z - aa.x) + 1.0f;
    const float ah = (aa.w - aa.y) + 1.0f;
    const float aarea = aw * ah;  // same op order as area_f

    float best = -1.0f;
    int barg = 0;
    int keep = 0;
#pragma unroll 8
    for (int g = 0; g < G_; ++g) {
      const float4 gg = *(const float4*)&s_gt[g * 4];  // LDS broadcast
      const float v = iou_f(aa.x, aa.y, aa.z, aa.w, aarea,
                            gg.x, gg.y, gg.z, gg.w, s_garea[g]);
      if (v > best) { best = v; barg = g; }  // first-occurrence argmax
      keep |= (v == s_gtmax[g]);             // bit-exact vs K1
    }

    int cc = -1;
    if (best >= 0.6f) cc = 1;
    if (best <= 0.3f) cc = 0;
    if (keep) cc = 1;
    cls0[b * N_ + n] = cc;                       // coalesced
    if (b == B_ - 1 && cc == 1) atomicAdd(&s_pc, 1);

    const float m0 = s_gt[barg * 4 + 0], m1 = s_gt[barg * 4 + 1];
    const float m2 = s_gt[barg * 4 + 2], m3 = s_gt[barg * 4 + 3];
    const float gw = (m2 - m0) + 1.0f;
    const float gh = (m3 - m1) + 1.0f;
    const float acx = aa.x + 0.5f * aw;
    const float acy = aa.y + 0.5f * ah;
    const float gcx = m0 + 0.5f * gw;
    const float gcy = m1 + 0.5f * gh;
    s_bt[0][nl] = (gcx - acx) / aw;
    s_bt[1][nl] = (gcy - acy) / ah;
    s_bt[2][nl] = logf(gw / aw);
    s_bt[3][nl] = logf(gh / ah);

    out[MO_OFF + b * N_ + n] = best;             // coalesced
  }
  __syncthreads();

  if (t == 0 && b == B_ - 1 && s_pc > 0) atomicAdd(poscnt, s_pc);

  // bt writeback: for (ch,a) the 125 spats are contiguous in out.
  // o in [0,2500): ch = o/625, a = (o%625)/125, sp = o%125; nl = sp*5 + a.
  float* __restrict__ out_bt = out + BT_OFF;
#pragma unroll
  for (int k = 0; k < 10; ++k) {
    const int o = k * 256 + t;
    if (o < 2500) {
      const int ch = o / 625;
      const int r  = o % 625;
      const int a  = r / 125;
      const int sp = r % 125;
      out_bt[((b * 4 + ch) * A_ + a) * (S_ * S_) + q * 125 + sp] =
          s_bt[ch][sp * 5 + a];
    }
  }
}

// ---- K3: per-batch caps (first 16 pos / first 64 neg) + cls + bw ----------
__global__ __launch_bounds__(256) void k3_caps_bw(
    float* __restrict__ out, const int* __restrict__ cls0,
    const int* __restrict__ poscnt) {
  const int b = blockIdx.x;
  const int t = threadIdx.x;
  __shared__ int s_c[N_];   // cls0 (int), then capped cls (float bits)
  __shared__ int s_p[256];
  __shared__ int s_n[256];

  // coalesced stage-in
#pragma unroll
  for (int k = 0; k < 13; ++k) {
    const int i = k * 256 + t;
    if (i < N_) s_c[i] = cls0[b * N_ + i];
  }
  __syncthreads();

  const int n0 = t * 13;
  int cvals[13];
  int myp = 0, myn = 0;
#pragma unroll
  for (int k = 0; k < 13; ++k) {
    const int n = n0 + k;
    int cc = -1;
    if (n < N_) {
      cc = s_c[n];
      if (cc == 1) ++myp;
      else if (cc == 0) ++myn;
    }
    cvals[k] = cc;
  }
  s_p[t] = myp;
  s_n[t] = myn;
  __syncthreads();
  for (int off = 1; off < 256; off <<= 1) {
    int vp = 0, vn = 0;
    if (t >= off) { vp = s_p[t - off]; vn = s_n[t - off]; }
    __syncthreads();
    s_p[t] += vp;
    s_n[t] += vn;
    __syncthreads();
  }

  int runp = s_p[t] - myp;  // exclusive prefix
  int runn = s_n[t] - myn;
#pragma unroll
  for (int k = 0; k < 13; ++k) {
    const int n = n0 + k;
    if (n >= N_) break;
    int cc = cvals[k];
    if (cc == 1) {
      if (++runp > POSN) cc = -1;
    } else if (cc == 0) {
      if (++runn > TOTN) cc = -1;
    }
    s_c[n] = __float_as_int((float)cc);  // own slot, no race
  }
  __syncthreads();

  // pos_num = min(pre-cap positives of batch 127, 16); bw = cls==1 ? 1/p : 0
  const int pc = poscnt[0];
  const float inv = 1.0f / (float)((pc < POSN) ? pc : POSN);

  // coalesced transposed write: o = a*625 + spat, n = spat*5 + a
#pragma unroll
  for (int k = 0; k < 13; ++k) {
    const int o = k * 256 + t;
    if (o < N_) {
      const int a  = o / 625;
      const int sp = o % 625;
      const float v = __int_as_float(s_c[sp * 5 + a]);
      out[CLS_OFF + b * N_ + o] = v;
      out[BW_OFF + b * N_ + o] = (v == 1.0f) ? inv : 0.0f;
    }
  }
}

extern "C" void kernel_launch(void* const* d_in, const int* in_sizes, int n_in,
                              void* d_out, int out_size, void* d_ws,
                              size_t ws_size, hipStream_t stream) {
  const float* gt = (const float*)d_in[0];       // (128,64,4)
  const float* anchors = (const float*)d_in[1];  // (3125,4)
  float* out = (float*)d_out;
  int* poscnt = (int*)d_ws;                      // [0]
  float* gtmax = (float*)d_ws + 64;              // 8192 floats
  int* cls0 = (int*)d_ws + 64 + B_ * G_;         // 400000 ints

  // Ordering between dispatches on `stream` guarantees visibility:
  // K1 zeroes poscnt & fills gtmax; K2 consumes gtmax, produces cls0+poscnt;
  // K3 consumes cls0+poscnt. No memsets needed.
  k1_gtmax<<<2048, 256, 0, stream>>>(gt, anchors, gtmax, poscnt);
  k2_anchor<<<dim3(5, B_), 256, 0, stream>>>(gt, anchors, gtmax, out, cls0,
                                             poscnt);
  k3_caps_bw<<<B_, 256, 0, stream>>>(out, cls0, poscnt);
}

// Round 6
// 113.717 us; speedup vs baseline: 1.1398x; 1.1398x over previous
//
#include <hip/hip_runtime.h>

// AnchorTarget (pysot) for b=128, G=64, SCORE=25, A=5, STRIDE=8.
// Outputs concatenated as float32: cls(128,5,25,25) | bt(128,4,5,25,25) |
// bw(128,5,25,25) | max_ov(128,3125). Total 2,800,000 floats.
//
// Round 6: 3 dispatches.
//   K1: gtmax — 2 (b,g) pairs per wave (halves L2 anchor traffic, which was
//       over the 34.5 TB/s L2 ceiling at 1 pair/wave), zero poscnt.
//   K2: per-anchor row, grid (13,128) for 26 waves/CU (r5's 640-block layout
//       regressed 6 us from occupancy loss), direct stores, batch-127
//       positive count -> poscnt.
//   K3: caps scan + cls + bw, LDS-staged coalesced IO.
// keep-test float equality protected by contract(off) in shared iou_f.

namespace {
constexpr int B_   = 128;
constexpr int N_   = 3125;   // 25*25*5
constexpr int G_   = 64;
constexpr int A_   = 5;
constexpr int S_   = 25;
constexpr int POSN = 16;
constexpr int TOTN = 64;

constexpr int CLS_OFF = 0;
constexpr int BT_OFF  = B_ * A_ * S_ * S_;              // 400000
constexpr int BW_OFF  = BT_OFF + B_ * 4 * A_ * S_ * S_; // 2000000
constexpr int MO_OFF  = BW_OFF + B_ * A_ * S_ * S_;     // 2400000
}

__device__ __forceinline__ float area_f(float x0, float y0, float x1, float y1) {
#pragma clang fp contract(off)
  return ((x1 - x0) + 1.0f) * ((y1 - y0) + 1.0f);
}

__device__ __forceinline__ float iou_f(float a0, float a1, float a2, float a3,
                                       float aarea, float g0, float g1,
                                       float g2, float g3, float garea) {
#pragma clang fp contract(off)
  // exactly mirrors numpy op order: ((min-max)+1), clip, mul, (a+g)-inter, div
  float ix = (fminf(a2, g2) - fmaxf(a0, g0)) + 1.0f;
  float iy = (fminf(a3, g3) - fmaxf(a1, g1)) + 1.0f;
  ix = fmaxf(ix, 0.0f);
  iy = fmaxf(iy, 0.0f);
  float inter = ix * iy;
  return inter / ((aarea + garea) - inter);
}

// ---- K1: gt_max[b][g] = max_n iou(n,g); 2 pairs/wave; zero poscnt ---------
// 4096 waves (1024 blk x 256 thr); wave w -> (b, g0) and (b, g0+1).
__global__ __launch_bounds__(256) void k1_gtmax(
    const float* __restrict__ gt,       // (128,64,4)
    const float* __restrict__ anchors,  // (3125,4)
    float* __restrict__ gtmax,          // (128,64)
    int* __restrict__ poscnt) {
#pragma clang fp contract(off)
  if (blockIdx.x == 0 && threadIdx.x == 0) poscnt[0] = 0;

  const int t    = threadIdx.x;
  const int lane = t & 63;
  const int w    = blockIdx.x * 4 + (t >> 6);  // 0..4095
  const int p0   = w * 2;
  const int b    = p0 >> 6;
  const int g0   = p0 & 63;  // even

  const float4 gg0 = ((const float4*)gt)[b * G_ + g0];
  const float4 gg1 = ((const float4*)gt)[b * G_ + g0 + 1];
  const float ga0 = area_f(gg0.x, gg0.y, gg0.z, gg0.w);
  const float ga1 = area_f(gg1.x, gg1.y, gg1.z, gg1.w);

  float m0 = 0.0f, m1 = 0.0f;  // iou >= 0
#pragma unroll 4
  for (int i = 0; i < 48; ++i) {
    const int n = i * 64 + lane;  // per-lane coalesced
    const float4 aa = ((const float4*)anchors)[n];
    const float aarea = area_f(aa.x, aa.y, aa.z, aa.w);
    m0 = fmaxf(m0, iou_f(aa.x, aa.y, aa.z, aa.w, aarea,
                         gg0.x, gg0.y, gg0.z, gg0.w, ga0));
    m1 = fmaxf(m1, iou_f(aa.x, aa.y, aa.z, aa.w, aarea,
                         gg1.x, gg1.y, gg1.z, gg1.w, ga1));
  }
  {
    const int n = 48 * 64 + lane;
    if (n < N_) {
      const float4 aa = ((const float4*)anchors)[n];
      const float aarea = area_f(aa.x, aa.y, aa.z, aa.w);
      m0 = fmaxf(m0, iou_f(aa.x, aa.y, aa.z, aa.w, aarea,
                           gg0.x, gg0.y, gg0.z, gg0.w, ga0));
      m1 = fmaxf(m1, iou_f(aa.x, aa.y, aa.z, aa.w, aarea,
                           gg1.x, gg1.y, gg1.z, gg1.w, ga1));
    }
  }
#pragma unroll
  for (int off = 32; off > 0; off >>= 1) {
    m0 = fmaxf(m0, __shfl_xor(m0, off, 64));
    m1 = fmaxf(m1, __shfl_xor(m1, off, 64));
  }
  if (lane == 0) {
    gtmax[p0]     = m0;
    gtmax[p0 + 1] = m1;
  }
}

// ---- K2: per-anchor row -> cls0, bt, max_ov, poscnt -----------------------
// Grid (13, 128), 256 thr, 1 anchor per thread (26 waves/CU).
__global__ __launch_bounds__(256) void k2_anchor(
    const float* __restrict__ gt, const float* __restrict__ anchors,
    const float* __restrict__ gtmax, float* __restrict__ out,
    int* __restrict__ cls0, int* __restrict__ poscnt) {
#pragma clang fp contract(off)
  const int b = blockIdx.y;
  const int t = threadIdx.x;
  const int n = blockIdx.x * 256 + t;

  __shared__ float s_gt[G_ * 4];
  __shared__ float s_garea[G_];
  __shared__ float s_gtmax[G_];
  __shared__ int   s_pc;

  if (t == 0) s_pc = 0;
  s_gt[t] = gt[b * G_ * 4 + t];  // 256 floats == whole gt row
  __syncthreads();
  if (t < G_) {
    s_garea[t] =
        area_f(s_gt[t * 4 + 0], s_gt[t * 4 + 1], s_gt[t * 4 + 2], s_gt[t * 4 + 3]);
    const float v = gtmax[b * G_ + t];
    s_gtmax[t] = (v == 0.0f) ? 1e-5f : v;
  }
  __syncthreads();

  if (n < N_) {
    const float4 aa = ((const float4*)anchors)[n];
    const float aw = (aa.z - aa.x) + 1.0f;
    const float ah = (aa.w - aa.y) + 1.0f;
    const float aarea = aw * ah;  // same op order as area_f

    float best = -1.0f;
    int barg = 0;
    int keep = 0;
#pragma unroll 8
    for (int g = 0; g < G_; ++g) {
      const float4 gg = *(const float4*)&s_gt[g * 4];  // LDS broadcast
      const float v = iou_f(aa.x, aa.y, aa.z, aa.w, aarea,
                            gg.x, gg.y, gg.z, gg.w, s_garea[g]);
      if (v > best) { best = v; barg = g; }  // first-occurrence argmax
      keep |= (v == s_gtmax[g]);             // bit-exact vs K1
    }

    int cc = -1;
    if (best >= 0.6f) cc = 1;
    if (best <= 0.3f) cc = 0;
    if (keep) cc = 1;
    cls0[b * N_ + n] = cc;  // coalesced
    if (b == B_ - 1 && cc == 1) atomicAdd(&s_pc, 1);

    const float m0 = s_gt[barg * 4 + 0], m1 = s_gt[barg * 4 + 1];
    const float m2 = s_gt[barg * 4 + 2], m3 = s_gt[barg * 4 + 3];
    const float gw = (m2 - m0) + 1.0f;
    const float gh = (m3 - m1) + 1.0f;
    const float acx = aa.x + 0.5f * aw;
    const float acy = aa.y + 0.5f * ah;
    const float gcx = m0 + 0.5f * gw;
    const float gcy = m1 + 0.5f * gh;
    const float dx = (gcx - acx) / aw;
    const float dy = (gcy - acy) / ah;
    const float dw = logf(gw / aw);
    const float dh = logf(gh / ah);

    // layout: n = (y*25 + x)*5 + a
    const int a = n % A_;
    const int rem = n / A_;
    const int x = rem % S_;
    const int y = rem / S_;
    const int spat = y * S_ + x;

    float* __restrict__ out_bt = out + BT_OFF;
    const int btb = ((b * 4 + 0) * A_ + a) * (S_ * S_) + spat;
    out_bt[btb + 0 * A_ * S_ * S_] = dx;
    out_bt[btb + 1 * A_ * S_ * S_] = dy;
    out_bt[btb + 2 * A_ * S_ * S_] = dw;
    out_bt[btb + 3 * A_ * S_ * S_] = dh;

    out[MO_OFF + b * N_ + n] = best;  // coalesced
  }
  __syncthreads();
  if (t == 0 && b == B_ - 1 && s_pc > 0) atomicAdd(poscnt, s_pc);
}

// ---- K3: per-batch caps (first 16 pos / first 64 neg) + cls + bw ----------
__global__ __launch_bounds__(256) void k3_caps_bw(
    float* __restrict__ out, const int* __restrict__ cls0,
    const int* __restrict__ poscnt) {
  const int b = blockIdx.x;
  const int t = threadIdx.x;
  __shared__ int s_c[N_];   // cls0 (int), then capped cls (float bits)
  __shared__ int s_p[256];
  __shared__ int s_n[256];

  // coalesced stage-in
#pragma unroll
  for (int k = 0; k < 13; ++k) {
    const int i = k * 256 + t;
    if (i < N_) s_c[i] = cls0[b * N_ + i];
  }
  __syncthreads();

  const int n0 = t * 13;
  int cvals[13];
  int myp = 0, myn = 0;
#pragma unroll
  for (int k = 0; k < 13; ++k) {
    const int n = n0 + k;
    int cc = -1;
    if (n < N_) {
      cc = s_c[n];
      if (cc == 1) ++myp;
      else if (cc == 0) ++myn;
    }
    cvals[k] = cc;
  }
  s_p[t] = myp;
  s_n[t] = myn;
  __syncthreads();
  for (int off = 1; off < 256; off <<= 1) {
    int vp = 0, vn = 0;
    if (t >= off) { vp = s_p[t - off]; vn = s_n[t - off]; }
    __syncthreads();
    s_p[t] += vp;
    s_n[t] += vn;
    __syncthreads();
  }

  int runp = s_p[t] - myp;  // exclusive prefix
  int runn = s_n[t] - myn;
#pragma unroll
  for (int k = 0; k < 13; ++k) {
    const int n = n0 + k;
    if (n >= N_) break;
    int cc = cvals[k];
    if (cc == 1) {
      if (++runp > POSN) cc = -1;
    } else if (cc == 0) {
      if (++runn > TOTN) cc = -1;
    }
    s_c[n] = __float_as_int((float)cc);  // own slot, no race
  }
  __syncthreads();

  // pos_num = min(pre-cap positives of batch 127, 16); bw = cls==1 ? 1/p : 0
  const int pc = poscnt[0];
  const float inv = 1.0f / (float)((pc < POSN) ? pc : POSN);

  // coalesced transposed write: o = a*625 + spat, n = spat*5 + a
#pragma unroll
  for (int k = 0; k < 13; ++k) {
    const int o = k * 256 + t;
    if (o < N_) {
      const int a  = o / 625;
      const int sp = o % 625;
      const float v = __int_as_float(s_c[sp * 5 + a]);
      out[CLS_OFF + b * N_ + o] = v;
      out[BW_OFF + b * N_ + o] = (v == 1.0f) ? inv : 0.0f;
    }
  }
}

extern "C" void kernel_launch(void* const* d_in, const int* in_sizes, int n_in,
                              void* d_out, int out_size, void* d_ws,
                              size_t ws_size, hipStream_t stream) {
  const float* gt = (const float*)d_in[0];       // (128,64,4)
  const float* anchors = (const float*)d_in[1];  // (3125,4)
  float* out = (float*)d_out;
  int* poscnt = (int*)d_ws;                      // [0]
  float* gtmax = (float*)d_ws + 64;              // 8192 floats
  int* cls0 = (int*)d_ws + 64 + B_ * G_;         // 400000 ints

  // Stream ordering: K1 zeroes poscnt & fills gtmax; K2 consumes gtmax,
  // produces cls0+poscnt; K3 consumes cls0+poscnt. No memsets needed.
  k1_gtmax<<<1024, 256, 0, stream>>>(gt, anchors, gtmax, poscnt);
  k2_anchor<<<dim3(13, B_), 256, 0, stream>>>(gt, anchors, gtmax, out, cls0,
                                              poscnt);
  k3_caps_bw<<<B_, 256, 0, stream>>>(out, cls0, poscnt);
}